// Round 1
// baseline (721.220 us; speedup 1.0000x reference)
//
#include <hip/hip_runtime.h>

#define K_CENTERS 500
#define DIM 768
#define N_ROWS (16 * 4096)

#define BR 64    // rows per block
#define BK 128   // centers per k-tile
#define DT 16    // d-tile depth

// ---------------------------------------------------------------------------
// Pre-kernel: csq[k] = ||c_k||^2. One wave per center.
// ---------------------------------------------------------------------------
__global__ void csq_kernel(const float* __restrict__ c, float* __restrict__ csq) {
    int wid  = (blockIdx.x * blockDim.x + threadIdx.x) >> 6;
    int lane = threadIdx.x & 63;
    if (wid >= K_CENTERS) return;
    const float* row = c + (size_t)wid * DIM;
    float s = 0.f;
    #pragma unroll
    for (int j = 0; j < DIM / 64; ++j) {
        float v = row[lane + j * 64];
        s += v * v;
    }
    #pragma unroll
    for (int m = 32; m; m >>= 1) s += __shfl_xor(s, m, 64);
    if (lane == 0) csq[wid] = s;
}

// ---------------------------------------------------------------------------
// Main kernel: each block = 64 rows x all 500 centers.
// Thread grid 16x16: ty = row group (4 rows each), tx = center group (8 each).
// K-tiles of 128 centers; d-tiles of 16 staged transposed in LDS so fragment
// reads are ds_read_b128.
// b-fragment mapping: thread tx owns centers {tx*4..tx*4+3} and
// {64+tx*4..64+tx*4+3} within the k-tile, so each b128 read covers a
// contiguous 256B LDS region (2-way bank aliasing = free, vs 4-way for
// the naive tx*8 mapping).
// ---------------------------------------------------------------------------
__global__ __launch_bounds__(256) void kmeans_assign(
        const float* __restrict__ x, const float* __restrict__ c,
        const float* __restrict__ csq, int* __restrict__ out) {
    __shared__ float xs[DT][BR];   // [16][64], transposed: xs[d][row]
    __shared__ float cs[DT][BK];   // [16][128], transposed: cs[d][k]

    const int tid = threadIdx.x;
    const int tx  = tid & 15;   // center group
    const int ty  = tid >> 4;   // row group
    const int rowBase = blockIdx.x * BR;

    // staging indices
    const int xr  = tid >> 2;   // 0..63 : row (for x) / k_local (for c)
    const int xdc = tid & 3;    // 0..3  : which float4 chunk of the 16-wide d-tile

    float bestv[4] = {INFINITY, INFINITY, INFINITY, INFINITY};
    int   besti[4] = {0, 0, 0, 0};

    for (int kt = 0; kt < K_CENTERS; kt += BK) {
        float dots[4][8];
        #pragma unroll
        for (int i = 0; i < 4; ++i)
            #pragma unroll
            for (int j = 0; j < 8; ++j) dots[i][j] = 0.f;

        for (int dt = 0; dt < DIM; dt += DT) {
            // ---- issue global loads (before barrier; latency overlaps) ----
            float4 xv = *reinterpret_cast<const float4*>(
                &x[(size_t)(rowBase + xr) * DIM + dt + xdc * 4]);

            int k0 = kt + xr;        // first 64 centers of tile
            int k1 = kt + xr + 64;   // second 64 centers of tile
            float4 cv0 = make_float4(0.f, 0.f, 0.f, 0.f);
            float4 cv1 = make_float4(0.f, 0.f, 0.f, 0.f);
            if (k0 < K_CENTERS)
                cv0 = *reinterpret_cast<const float4*>(&c[(size_t)k0 * DIM + dt + xdc * 4]);
            if (k1 < K_CENTERS)
                cv1 = *reinterpret_cast<const float4*>(&c[(size_t)k1 * DIM + dt + xdc * 4]);

            __syncthreads();   // previous compute phase done reading LDS

            // ---- scatter-write transposed tiles ----
            xs[xdc * 4 + 0][xr] = xv.x;
            xs[xdc * 4 + 1][xr] = xv.y;
            xs[xdc * 4 + 2][xr] = xv.z;
            xs[xdc * 4 + 3][xr] = xv.w;

            cs[xdc * 4 + 0][xr] = cv0.x;
            cs[xdc * 4 + 1][xr] = cv0.y;
            cs[xdc * 4 + 2][xr] = cv0.z;
            cs[xdc * 4 + 3][xr] = cv0.w;
            cs[xdc * 4 + 0][xr + 64] = cv1.x;
            cs[xdc * 4 + 1][xr + 64] = cv1.y;
            cs[xdc * 4 + 2][xr + 64] = cv1.z;
            cs[xdc * 4 + 3][xr + 64] = cv1.w;

            __syncthreads();

            // ---- register-tiled FMA: 16 dd x (4 rows x 8 centers) ----
            #pragma unroll
            for (int dd = 0; dd < DT; ++dd) {
                float4 av = *reinterpret_cast<const float4*>(&xs[dd][ty * 4]);
                float4 b0 = *reinterpret_cast<const float4*>(&cs[dd][tx * 4]);
                float4 b1 = *reinterpret_cast<const float4*>(&cs[dd][64 + tx * 4]);
                float a[4] = {av.x, av.y, av.z, av.w};
                float b[8] = {b0.x, b0.y, b0.z, b0.w, b1.x, b1.y, b1.z, b1.w};
                #pragma unroll
                for (int i = 0; i < 4; ++i)
                    #pragma unroll
                    for (int j = 0; j < 8; ++j)
                        dots[i][j] = fmaf(a[i], b[j], dots[i][j]);
            }
        }

        // ---- fold this k-tile into the running argmin ----
        #pragma unroll
        for (int j = 0; j < 8; ++j) {
            int k = kt + (j < 4 ? tx * 4 + j : 64 + tx * 4 + (j - 4));
            if (k < K_CENTERS) {
                float cq = csq[k];
                #pragma unroll
                for (int i = 0; i < 4; ++i) {
                    float dist = fmaf(-2.f, dots[i][j], cq);
                    if (dist < bestv[i]) { bestv[i] = dist; besti[i] = k; }
                    else if (dist == bestv[i] && k < besti[i]) besti[i] = k;
                }
            }
        }
        __syncthreads();   // before next k-tile overwrites LDS
    }

    // ---- reduce across the 16 tx-threads sharing each row ----
    #pragma unroll
    for (int m = 1; m < 16; m <<= 1) {
        #pragma unroll
        for (int i = 0; i < 4; ++i) {
            float ov = __shfl_xor(bestv[i], m, 64);
            int   oi = __shfl_xor(besti[i], m, 64);
            if (ov < bestv[i] || (ov == bestv[i] && oi < besti[i])) {
                bestv[i] = ov; besti[i] = oi;
            }
        }
    }
    if (tx == 0) {
        #pragma unroll
        for (int i = 0; i < 4; ++i)
            out[rowBase + ty * 4 + i] = besti[i];
    }
}

extern "C" void kernel_launch(void* const* d_in, const int* in_sizes, int n_in,
                              void* d_out, int out_size, void* d_ws, size_t ws_size,
                              hipStream_t stream) {
    const float* x = (const float*)d_in[0];
    const float* c = (const float*)d_in[1];
    float* csq = (float*)d_ws;          // 500 floats of scratch
    int*   out = (int*)d_out;

    // csq: 500 waves = 125 blocks * 256 threads
    csq_kernel<<<dim3((K_CENTERS * 64 + 255) / 256), dim3(256), 0, stream>>>(c, csq);

    // main: 65536/64 = 1024 blocks
    kmeans_assign<<<dim3(N_ROWS / BR), dim3(256), 0, stream>>>(x, c, csq, out);
}

// Round 2
// 381.538 us; speedup vs baseline: 1.8903x; 1.8903x over previous
//
#include <hip/hip_runtime.h>

#define K_C    500
#define KPAD   512
#define DIM    768
#define NROWS  65536
#define BM     64
#define BK     32
#define NKT    (DIM / BK)      // 24 K-tiles
#define THREADS 512
#define TAU    0.125f

// ---- d_ws layout (bytes) ----
// [0]        : int rescue_count
// [64]       : float csq[512]
// [4096]     : int  rescue_list[65536]
// [270336]   : c_hi tiles  : [24][4][512] 16B units (786432 B)
// [1056768]  : c_lo tiles  : same (786432 B)      -> total ~1.76 MB
#define WS_CSQ  64
#define WS_LIST 4096
#define WS_CHI  270336
#define WS_CLO  (270336 + 786432)

typedef __attribute__((ext_vector_type(8)))  short bf16x8;
typedef __attribute__((ext_vector_type(16))) float f32x16;

__device__ __forceinline__ ushort f2bf(float f) {
    unsigned x = __float_as_uint(f);
    unsigned r = (x + 0x7fffu + ((x >> 16) & 1u)) >> 16;   // RNE
    return (ushort)r;
}
__device__ __forceinline__ float bf2f(ushort h) {
    return __uint_as_float(((unsigned)h) << 16);
}

#define GLOAD16(g, l)                                                        \
    __builtin_amdgcn_global_load_lds(                                        \
        (__attribute__((address_space(1))) void*)(g),                        \
        (__attribute__((address_space(3))) void*)(l), 16, 0, 0)

// ---------------------------------------------------------------------------
// Pre-kernel 1: convert centers fp32 -> (hi, lo) bf16 in chunk-major tile
// layout: unit u = kt*2048 + j*512 + r holds c[r][kt*32 + j*8 .. +7].
// Rows 500..511 padded with zeros. Also zeroes the rescue counter.
// 49152 threads = 192 blocks x 256.
// ---------------------------------------------------------------------------
__global__ void convert_kernel(const float* __restrict__ c, ushort* __restrict__ chi,
                               ushort* __restrict__ clo, int* __restrict__ count) {
    int gid = blockIdx.x * 256 + threadIdx.x;
    if (gid == 0) *count = 0;
    int kt = gid >> 11;           // /2048
    int u  = gid & 2047;
    int j  = u >> 9;              // /512
    int r  = u & 511;
    int kbase = kt * 32 + j * 8;

    ushort h[8], l[8];
    if (r < K_C) {
        #pragma unroll
        for (int e = 0; e < 8; ++e) {
            float v  = c[(size_t)r * DIM + kbase + e];
            ushort hb = f2bf(v);
            float  hv = bf2f(hb);
            ushort lb = f2bf(v - hv);
            h[e] = hb; l[e] = lb;
        }
    } else {
        #pragma unroll
        for (int e = 0; e < 8; ++e) { h[e] = 0; l[e] = 0; }
    }
    ushort* ph = chi + (size_t)gid * 8;
    ushort* pl = clo + (size_t)gid * 8;
    #pragma unroll
    for (int e = 0; e < 8; ++e) { ph[e] = h[e]; pl[e] = l[e]; }
}

// ---------------------------------------------------------------------------
// Pre-kernel 2: csq[k] = ||c_k||^2 in fp32 (from ORIGINAL fp32 centers).
// Pads 500..511 with +INF. 512 waves = 128 blocks x 256.
// ---------------------------------------------------------------------------
__global__ void csq_kernel(const float* __restrict__ c, float* __restrict__ csq) {
    int wid  = (blockIdx.x * blockDim.x + threadIdx.x) >> 6;
    int lane = threadIdx.x & 63;
    if (wid >= KPAD) return;
    if (wid >= K_C) { if (lane == 0) csq[wid] = INFINITY; return; }
    const float* row = c + (size_t)wid * DIM;
    float s = 0.f;
    #pragma unroll
    for (int j = 0; j < DIM / 64; ++j) {
        float v = row[lane + j * 64];
        s += v * v;
    }
    #pragma unroll
    for (int m = 32; m; m >>= 1) s += __shfl_xor(s, m, 64);
    if (lane == 0) csq[wid] = s;
}

// ---------------------------------------------------------------------------
// Main kernel: 64 rows x 512 centers per block, split-bf16 MFMA 32x32x16.
// 8 waves, wave w owns cols [w*64, w*64+64): 2 Mfrags x 2 Nfrags, acc 2x2xf32x16.
// B staged via global_load_lds from pre-swizzled ws tiles (conflict-free b128
// reads: 16B-unit slot-class = center%8). A converted fp32->hi/lo on the fly.
// Epilogue: per-row best/second/idx over 512 centers; margin < TAU rows are
// appended to the rescue list.
// ---------------------------------------------------------------------------
__global__ __launch_bounds__(THREADS, 2) void kmeans_mfma(
        const float* __restrict__ x, const char* __restrict__ ws,
        int* __restrict__ out) {
    __shared__ __align__(16) ushort Bh[4][KPAD][8];   // 32 KB
    __shared__ __align__(16) ushort Bl[4][KPAD][8];   // 32 KB
    __shared__ __align__(16) ushort Ah[4][BM][8];     // 4 KB
    __shared__ __align__(16) ushort Al[4][BM][8];     // 4 KB
    __shared__ float rv1[8][BM];                      // 2 KB
    __shared__ float rv2[8][BM];                      // 2 KB
    __shared__ int   ridx[8][BM];                     // 2 KB

    const int tid  = threadIdx.x;
    const int w    = tid >> 6;          // wave 0..7
    const int lane = tid & 63;
    const int l31  = lane & 31;
    const int lh   = lane >> 5;
    const int rowBase = blockIdx.x * BM;

    // A staging mapping: thread t -> row m, chunk j, half
    const int sm    = tid >> 3;         // 0..63 row
    const int ssub  = tid & 7;
    const int sj    = ssub >> 1;        // chunk 0..3
    const int shalf = ssub & 1;
    const float* xsrc = x + (size_t)(rowBase + sm) * DIM + sj * 8 + shalf * 4;

    const char* wsChi = ws + WS_CHI;
    const char* wsClo = ws + WS_CLO;
    const float* csq  = (const float*)(ws + WS_CSQ);
    int* count = (int*)ws;
    int* list  = (int*)(ws + WS_LIST);

    f32x16 acc[2][2] = {};

    for (int kt = 0; kt < NKT; ++kt) {
        // issue A global load before the barrier (latency overlaps tail compute)
        float4 xv = *reinterpret_cast<const float4*>(xsrc + kt * BK);

        __syncthreads();   // previous tile's readers done

        // ---- B: global_load_lds, 4 hi + 4 lo instrs per wave (1 KB each) ----
        {
            const char* srcH = wsChi + (size_t)kt * 32768 + w * 4096 + lane * 16;
            const char* srcL = wsClo + (size_t)kt * 32768 + w * 4096 + lane * 16;
            char* dstH = (char*)&Bh[0][0][0] + w * 4096;
            char* dstL = (char*)&Bl[0][0][0] + w * 4096;
            #pragma unroll
            for (int i = 0; i < 4; ++i) GLOAD16(srcH + i * 1024, dstH + i * 1024);
            #pragma unroll
            for (int i = 0; i < 4; ++i) GLOAD16(srcL + i * 1024, dstL + i * 1024);
        }

        // ---- A: convert + LDS write (hi/lo), 8B each ----
        {
            float vf[4] = {xv.x, xv.y, xv.z, xv.w};
            ushort h[4], l[4];
            #pragma unroll
            for (int e = 0; e < 4; ++e) {
                h[e] = f2bf(vf[e]);
                l[e] = f2bf(vf[e] - bf2f(h[e]));
            }
            *(ushort4*)&Ah[sj][sm][shalf * 4] = make_ushort4(h[0], h[1], h[2], h[3]);
            *(ushort4*)&Al[sj][sm][shalf * 4] = make_ushort4(l[0], l[1], l[2], l[3]);
        }

        __syncthreads();   // compiler drains vmcnt+lgkmcnt here

        // ---- compute: 2 k-steps of 16 ----
        #pragma unroll
        for (int ks = 0; ks < 2; ++ks) {
            const int j = ks * 2 + lh;    // k-chunk for this lane-half
            bf16x8 ah0 = *(const bf16x8*)&Ah[j][l31][0];
            bf16x8 ah1 = *(const bf16x8*)&Ah[j][32 + l31][0];
            bf16x8 al0 = *(const bf16x8*)&Al[j][l31][0];
            bf16x8 al1 = *(const bf16x8*)&Al[j][32 + l31][0];
            bf16x8 bh0 = *(const bf16x8*)&Bh[j][w * 64 + l31][0];
            bf16x8 bh1 = *(const bf16x8*)&Bh[j][w * 64 + 32 + l31][0];
            bf16x8 bl0 = *(const bf16x8*)&Bl[j][w * 64 + l31][0];
            bf16x8 bl1 = *(const bf16x8*)&Bl[j][w * 64 + 32 + l31][0];

            acc[0][0] = __builtin_amdgcn_mfma_f32_32x32x16_bf16(ah0, bh0, acc[0][0], 0, 0, 0);
            acc[0][0] = __builtin_amdgcn_mfma_f32_32x32x16_bf16(ah0, bl0, acc[0][0], 0, 0, 0);
            acc[0][0] = __builtin_amdgcn_mfma_f32_32x32x16_bf16(al0, bh0, acc[0][0], 0, 0, 0);

            acc[0][1] = __builtin_amdgcn_mfma_f32_32x32x16_bf16(ah0, bh1, acc[0][1], 0, 0, 0);
            acc[0][1] = __builtin_amdgcn_mfma_f32_32x32x16_bf16(ah0, bl1, acc[0][1], 0, 0, 0);
            acc[0][1] = __builtin_amdgcn_mfma_f32_32x32x16_bf16(al0, bh1, acc[0][1], 0, 0, 0);

            acc[1][0] = __builtin_amdgcn_mfma_f32_32x32x16_bf16(ah1, bh0, acc[1][0], 0, 0, 0);
            acc[1][0] = __builtin_amdgcn_mfma_f32_32x32x16_bf16(ah1, bl0, acc[1][0], 0, 0, 0);
            acc[1][0] = __builtin_amdgcn_mfma_f32_32x32x16_bf16(al1, bh0, acc[1][0], 0, 0, 0);

            acc[1][1] = __builtin_amdgcn_mfma_f32_32x32x16_bf16(ah1, bh1, acc[1][1], 0, 0, 0);
            acc[1][1] = __builtin_amdgcn_mfma_f32_32x32x16_bf16(ah1, bl1, acc[1][1], 0, 0, 0);
            acc[1][1] = __builtin_amdgcn_mfma_f32_32x32x16_bf16(al1, bh1, acc[1][1], 0, 0, 0);
        }
    }

    // ---- epilogue: per-row (best, second, idx) over this wave's 64 cols ----
    const int col0 = w * 64 + l31;
    const int col1 = col0 + 32;
    const float cq0 = csq[col0];
    const float cq1 = csq[col1];

    #pragma unroll
    for (int mf = 0; mf < 2; ++mf) {
        #pragma unroll
        for (int reg = 0; reg < 16; ++reg) {
            float v0 = fmaf(-2.f, acc[mf][0][reg], cq0);
            float v1 = fmaf(-2.f, acc[mf][1][reg], cq1);
            float b1, b2; int i1;
            if (v0 <= v1) { b1 = v0; b2 = v1; i1 = col0; }
            else          { b1 = v1; b2 = v0; i1 = col1; }
            #pragma unroll
            for (int m = 1; m < 32; m <<= 1) {
                float o1 = __shfl_xor(b1, m, 64);
                float o2 = __shfl_xor(b2, m, 64);
                int   oi = __shfl_xor(i1, m, 64);
                b2 = fminf(fminf(b2, o2), fmaxf(b1, o1));
                if (o1 < b1 || (o1 == b1 && oi < i1)) { b1 = o1; i1 = oi; }
            }
            int row = mf * 32 + (reg & 3) + 8 * (reg >> 2) + 4 * lh;
            if (l31 == 0) { rv1[w][row] = b1; rv2[w][row] = b2; ridx[w][row] = i1; }
        }
    }
    __syncthreads();

    // ---- merge 8 waves, write out, flag tight-margin rows ----
    if (tid < BM) {
        float b1 = INFINITY, b2 = INFINITY; int i1 = 0;
        #pragma unroll
        for (int ww = 0; ww < 8; ++ww) {
            float a1 = rv1[ww][tid], a2 = rv2[ww][tid];
            int   ai = ridx[ww][tid];
            b2 = fminf(fminf(b2, a2), fmaxf(b1, a1));
            if (a1 < b1 || (a1 == b1 && ai < i1)) { b1 = a1; i1 = ai; }
        }
        out[rowBase + tid] = i1;
        if (b2 - b1 < TAU) {
            int p = atomicAdd(count, 1);
            list[p] = rowBase + tid;
        }
    }
}

// ---------------------------------------------------------------------------
// Rescue: exact fp32 recompute for flagged rows. Fixed grid, loops over list.
// ---------------------------------------------------------------------------
__global__ void rescue_kernel(const float* __restrict__ x, const float* __restrict__ c,
                              const char* __restrict__ ws, int* __restrict__ out) {
    __shared__ float xrow[DIM];
    __shared__ float rv[256];
    __shared__ int   ri[256];
    const float* csq = (const float*)(ws + WS_CSQ);
    const int* list  = (const int*)(ws + WS_LIST);
    const int n = *(const int*)ws;
    const int tid = threadIdx.x;

    for (int it = blockIdx.x; it < n; it += gridDim.x) {
        int row = list[it];
        for (int d = tid; d < DIM; d += 256) xrow[d] = x[(size_t)row * DIM + d];
        __syncthreads();

        float bv = INFINITY; int bi = 0;
        for (int k = tid; k < K_C; k += 256) {
            const float* crow = c + (size_t)k * DIM;
            float dot = 0.f;
            #pragma unroll 4
            for (int d = 0; d < DIM; d += 4) {
                float4 cv = *reinterpret_cast<const float4*>(&crow[d]);
                dot = fmaf(xrow[d + 0], cv.x, dot);
                dot = fmaf(xrow[d + 1], cv.y, dot);
                dot = fmaf(xrow[d + 2], cv.z, dot);
                dot = fmaf(xrow[d + 3], cv.w, dot);
            }
            float dist = fmaf(-2.f, dot, csq[k]);
            if (dist < bv || (dist == bv && k < bi)) { bv = dist; bi = k; }
        }
        rv[tid] = bv; ri[tid] = bi;
        __syncthreads();
        for (int s = 128; s; s >>= 1) {
            if (tid < s) {
                if (rv[tid + s] < rv[tid] ||
                    (rv[tid + s] == rv[tid] && ri[tid + s] < ri[tid])) {
                    rv[tid] = rv[tid + s]; ri[tid] = ri[tid + s];
                }
            }
            __syncthreads();
        }
        if (tid == 0) out[row] = ri[0];
        __syncthreads();   // before next iteration overwrites xrow
    }
}

extern "C" void kernel_launch(void* const* d_in, const int* in_sizes, int n_in,
                              void* d_out, int out_size, void* d_ws, size_t ws_size,
                              hipStream_t stream) {
    const float* x = (const float*)d_in[0];
    const float* c = (const float*)d_in[1];
    char* ws = (char*)d_ws;
    int* out = (int*)d_out;

    convert_kernel<<<dim3(192), dim3(256), 0, stream>>>(
        c, (ushort*)(ws + WS_CHI), (ushort*)(ws + WS_CLO), (int*)ws);
    csq_kernel<<<dim3(128), dim3(256), 0, stream>>>(c, (float*)(ws + WS_CSQ));
    kmeans_mfma<<<dim3(NROWS / BM), dim3(THREADS), 0, stream>>>(x, ws, out);
    rescue_kernel<<<dim3(128), dim3(256), 0, stream>>>(x, c, ws, out);
}

// Round 4
// 264.495 us; speedup vs baseline: 2.7268x; 1.4425x over previous
//
#include <hip/hip_runtime.h>

#define K_C    500
#define KPAD   512
#define DIM    768
#define NROWS  65536
#define BM     128
#define BK     32
#define NKT    (DIM / BK)      // 24 K-tiles
#define THREADS 512
#define TAU    0.05f

// Per-buffer LDS stride for B double-buffer: 4 chunks x 512 centers x 8 ushorts
#define BBUF_BYTES 32768

// ---- d_ws layout (bytes) ----
#define WS_CSQ  64
#define WS_LIST 4096
#define WS_CHI  270336
#define WS_CLO  (270336 + 786432)

typedef __attribute__((ext_vector_type(8)))  short bf16x8;
typedef __attribute__((ext_vector_type(16))) float f32x16;

__device__ __forceinline__ ushort f2bf(float f) {
    unsigned x = __float_as_uint(f);
    unsigned r = (x + 0x7fffu + ((x >> 16) & 1u)) >> 16;   // RNE
    return (ushort)r;
}
__device__ __forceinline__ float bf2f(ushort h) {
    return __uint_as_float(((unsigned)h) << 16);
}

#define GLOAD16(g, l)                                                        \
    __builtin_amdgcn_global_load_lds(                                        \
        (__attribute__((address_space(1))) void*)(g),                        \
        (__attribute__((address_space(3))) void*)(l), 16, 0, 0)

// ---------------------------------------------------------------------------
// Pre-kernel 1: centers fp32 -> (hi, lo) bf16, chunk-major tile layout
// unit u = kt*2048 + j*512 + r holds c[r][kt*32 + j*8 .. +7]. Zero-pads
// rows 500..511 and zeroes the rescue counter.
// ---------------------------------------------------------------------------
__global__ void convert_kernel(const float* __restrict__ c, ushort* __restrict__ chi,
                               ushort* __restrict__ clo, int* __restrict__ count) {
    int gid = blockIdx.x * 256 + threadIdx.x;
    if (gid == 0) *count = 0;
    int kt = gid >> 11;
    int u  = gid & 2047;
    int j  = u >> 9;
    int r  = u & 511;
    int kbase = kt * 32 + j * 8;

    ushort h[8], l[8];
    if (r < K_C) {
        #pragma unroll
        for (int e = 0; e < 8; ++e) {
            float v  = c[(size_t)r * DIM + kbase + e];
            ushort hb = f2bf(v);
            float  hv = bf2f(hb);
            ushort lb = f2bf(v - hv);
            h[e] = hb; l[e] = lb;
        }
    } else {
        #pragma unroll
        for (int e = 0; e < 8; ++e) { h[e] = 0; l[e] = 0; }
    }
    ushort* ph = chi + (size_t)gid * 8;
    ushort* pl = clo + (size_t)gid * 8;
    #pragma unroll
    for (int e = 0; e < 8; ++e) { ph[e] = h[e]; pl[e] = l[e]; }
}

// ---------------------------------------------------------------------------
// Pre-kernel 2: csq[k] = ||c_k||^2 fp32; pads 500..511 with +INF.
// ---------------------------------------------------------------------------
__global__ void csq_kernel(const float* __restrict__ c, float* __restrict__ csq) {
    int wid  = (blockIdx.x * blockDim.x + threadIdx.x) >> 6;
    int lane = threadIdx.x & 63;
    if (wid >= KPAD) return;
    if (wid >= K_C) { if (lane == 0) csq[wid] = INFINITY; return; }
    const float* row = c + (size_t)wid * DIM;
    float s = 0.f;
    #pragma unroll
    for (int j = 0; j < DIM / 64; ++j) {
        float v = row[lane + j * 64];
        s += v * v;
    }
    #pragma unroll
    for (int m = 32; m; m >>= 1) s += __shfl_xor(s, m, 64);
    if (lane == 0) csq[wid] = s;
}

// ---------------------------------------------------------------------------
// Main kernel: 128 rows x 512 centers per block. 8 waves = 2(m) x 4(n);
// per wave 2 Mfrags x 4 Nfrags of 32x32x16 MFMA, 3 MFMAs per frag pair
// (hi*hi + hi*lo + lo*hi). B double-buffered via global_load_lds prefetch
// issued at compute-phase start (drained by next top-of-loop barrier after
// a full compute phase -> no exposed vmcnt stall). A converted fp32->hi/lo
// in the compute phase; only the 2 ds_writes sit between barriers.
// BUGFIX vs round 3: per-buffer stride is 32768 B (was 65536 -> wrote past
// Bh into Bl/Ah, corrupting tiles).
// ---------------------------------------------------------------------------
__global__ __launch_bounds__(THREADS, 2) void kmeans_mfma(
        const float* __restrict__ x, const char* __restrict__ ws,
        int* __restrict__ out) {
    __shared__ __align__(16) ushort Bh[2][4][KPAD][8];   // 64 KB
    __shared__ __align__(16) ushort Bl[2][4][KPAD][8];   // 64 KB
    __shared__ __align__(16) ushort Ah[4][BM][8];        // 8 KB
    __shared__ __align__(16) ushort Al[4][BM][8];        // 8 KB
    __shared__ float rv1[4][BM];                         // 2 KB
    __shared__ float rv2[4][BM];                         // 2 KB
    __shared__ int   ridx[4][BM];                        // 2 KB

    const int tid  = threadIdx.x;
    const int w    = tid >> 6;          // wave 0..7
    const int lane = tid & 63;
    const int l31  = lane & 31;
    const int lh   = lane >> 5;
    const int wm   = w >> 2;            // 0..1 row half
    const int wn   = w & 3;             // 0..3 col quarter
    const int rowBase = blockIdx.x * BM;

    // A staging: thread t -> row t>>2 (0..127), k-chunk j = t&3
    const int srow = tid >> 2;
    const int sj   = tid & 3;
    const float* xsrc = x + (size_t)(rowBase + srow) * DIM + sj * 8;

    const char* wsChi = ws + WS_CHI;
    const char* wsClo = ws + WS_CLO;
    const float* csq  = (const float*)(ws + WS_CSQ);
    int* count = (int*)ws;
    int* list  = (int*)(ws + WS_LIST);

    f32x16 acc[2][4] = {};

    // ---- prologue: stage B tile 0 into buf 0; load+convert A tile 0 ----
    {
        const char* sH = wsChi + (size_t)0 * 32768 + w * 4096 + lane * 16;
        const char* sL = wsClo + (size_t)0 * 32768 + w * 4096 + lane * 16;
        char* dH = ((char*)Bh) + w * 4096;
        char* dL = ((char*)Bl) + w * 4096;
        #pragma unroll
        for (int i = 0; i < 4; ++i) GLOAD16(sH + i * 1024, dH + i * 1024);
        #pragma unroll
        for (int i = 0; i < 4; ++i) GLOAD16(sL + i * 1024, dL + i * 1024);
    }
    uint4 hv, lv;
    {
        float4 xa = *reinterpret_cast<const float4*>(xsrc);
        float4 xb = *reinterpret_cast<const float4*>(xsrc + 4);
        float v[8] = {xa.x, xa.y, xa.z, xa.w, xb.x, xb.y, xb.z, xb.w};
        uint h[8], l[8];
        #pragma unroll
        for (int e = 0; e < 8; ++e) {
            h[e] = f2bf(v[e]);
            l[e] = f2bf(v[e] - bf2f((ushort)h[e]));
        }
        hv = make_uint4(h[0] | (h[1] << 16), h[2] | (h[3] << 16),
                        h[4] | (h[5] << 16), h[6] | (h[7] << 16));
        lv = make_uint4(l[0] | (l[1] << 16), l[2] | (l[3] << 16),
                        l[4] | (l[5] << 16), l[6] | (l[7] << 16));
    }

    for (int kt = 0; kt < NKT; ++kt) {
        const int cur = kt & 1;

        __syncthreads();   // (a) prev compute done; drains B[cur] stage + x loads

        // ---- A write phase (pre-converted regs -> LDS) ----
        *reinterpret_cast<uint4*>(&Ah[sj][srow][0]) = hv;
        *reinterpret_cast<uint4*>(&Al[sj][srow][0]) = lv;

        __syncthreads();   // (b) A visible (lgkm drain only)

        // ---- prefetch next B tile + next A floats (live across compute) ----
        float4 xa, xb;
        if (kt + 1 < NKT) {
            const int nxt = cur ^ 1;
            const char* sH = wsChi + (size_t)(kt + 1) * 32768 + w * 4096 + lane * 16;
            const char* sL = wsClo + (size_t)(kt + 1) * 32768 + w * 4096 + lane * 16;
            char* dH = ((char*)Bh) + nxt * BBUF_BYTES + w * 4096;
            char* dL = ((char*)Bl) + nxt * BBUF_BYTES + w * 4096;
            #pragma unroll
            for (int i = 0; i < 4; ++i) GLOAD16(sH + i * 1024, dH + i * 1024);
            #pragma unroll
            for (int i = 0; i < 4; ++i) GLOAD16(sL + i * 1024, dL + i * 1024);
            xa = *reinterpret_cast<const float4*>(xsrc + (kt + 1) * BK);
            xb = *reinterpret_cast<const float4*>(xsrc + (kt + 1) * BK + 4);
        }

        // ---- compute: 2 k-steps of 16, 24 MFMAs each ----
        #pragma unroll
        for (int ks = 0; ks < 2; ++ks) {
            const int j = ks * 2 + lh;
            const ushort* pAh = &Ah[j][wm * 64 + l31][0];
            const ushort* pAl = &Al[j][wm * 64 + l31][0];
            bf16x8 ah0 = *(const bf16x8*)pAh;
            bf16x8 ah1 = *(const bf16x8*)(pAh + 32 * 8);
            bf16x8 al0 = *(const bf16x8*)pAl;
            bf16x8 al1 = *(const bf16x8*)(pAl + 32 * 8);

            const ushort* pBh = &Bh[cur][j][wn * 128 + l31][0];
            const ushort* pBl = &Bl[cur][j][wn * 128 + l31][0];
            #pragma unroll
            for (int nf = 0; nf < 4; ++nf) {
                bf16x8 bh = *(const bf16x8*)(pBh + nf * 32 * 8);
                bf16x8 bl = *(const bf16x8*)(pBl + nf * 32 * 8);
                acc[0][nf] = __builtin_amdgcn_mfma_f32_32x32x16_bf16(ah0, bh, acc[0][nf], 0, 0, 0);
                acc[0][nf] = __builtin_amdgcn_mfma_f32_32x32x16_bf16(ah0, bl, acc[0][nf], 0, 0, 0);
                acc[0][nf] = __builtin_amdgcn_mfma_f32_32x32x16_bf16(al0, bh, acc[0][nf], 0, 0, 0);
                acc[1][nf] = __builtin_amdgcn_mfma_f32_32x32x16_bf16(ah1, bh, acc[1][nf], 0, 0, 0);
                acc[1][nf] = __builtin_amdgcn_mfma_f32_32x32x16_bf16(ah1, bl, acc[1][nf], 0, 0, 0);
                acc[1][nf] = __builtin_amdgcn_mfma_f32_32x32x16_bf16(al1, bh, acc[1][nf], 0, 0, 0);
            }
        }

        // ---- convert next A tile (after compute in source; loads issued above) ----
        if (kt + 1 < NKT) {
            float v[8] = {xa.x, xa.y, xa.z, xa.w, xb.x, xb.y, xb.z, xb.w};
            uint h[8], l[8];
            #pragma unroll
            for (int e = 0; e < 8; ++e) {
                h[e] = f2bf(v[e]);
                l[e] = f2bf(v[e] - bf2f((ushort)h[e]));
            }
            hv = make_uint4(h[0] | (h[1] << 16), h[2] | (h[3] << 16),
                            h[4] | (h[5] << 16), h[6] | (h[7] << 16));
            lv = make_uint4(l[0] | (l[1] << 16), l[2] | (l[3] << 16),
                            l[4] | (l[5] << 16), l[6] | (l[7] << 16));
        }
    }

    // ---- epilogue: per-row (best, second, idx) over this wave's 128 cols ----
    float cq[4];
    #pragma unroll
    for (int nf = 0; nf < 4; ++nf) cq[nf] = csq[wn * 128 + nf * 32 + l31];

    #pragma unroll
    for (int mf = 0; mf < 2; ++mf) {
        #pragma unroll
        for (int reg = 0; reg < 16; ++reg) {
            float v[4]; int col[4];
            #pragma unroll
            for (int nf = 0; nf < 4; ++nf) {
                v[nf]   = fmaf(-2.f, acc[mf][nf][reg], cq[nf]);
                col[nf] = wn * 128 + nf * 32 + l31;
            }
            // 4-way tournament for (best, idx, second); ties -> lower col
            float paL, paH; int paI;
            if (v[1] < v[0]) { paL = v[1]; paI = col[1]; paH = v[0]; }
            else             { paL = v[0]; paI = col[0]; paH = v[1]; }
            float pbL, pbH; int pbI;
            if (v[3] < v[2]) { pbL = v[3]; pbI = col[3]; pbH = v[2]; }
            else             { pbL = v[2]; pbI = col[2]; pbH = v[3]; }
            float b1, b2; int i1;
            if (pbL < paL) { b1 = pbL; i1 = pbI; b2 = fminf(paL, pbH); }
            else           { b1 = paL; i1 = paI; b2 = fminf(pbL, paH); }
            // reduce across the 32 l31 lanes (same lh half)
            #pragma unroll
            for (int m = 1; m < 32; m <<= 1) {
                float o1 = __shfl_xor(b1, m, 64);
                float o2 = __shfl_xor(b2, m, 64);
                int   oi = __shfl_xor(i1, m, 64);
                b2 = fminf(fminf(b2, o2), fmaxf(b1, o1));
                if (o1 < b1 || (o1 == b1 && oi < i1)) { b1 = o1; i1 = oi; }
            }
            int row = wm * 64 + mf * 32 + (reg & 3) + 8 * (reg >> 2) + 4 * lh;
            if (l31 == 0) { rv1[wn][row] = b1; rv2[wn][row] = b2; ridx[wn][row] = i1; }
        }
    }
    __syncthreads();

    // ---- merge 4 col-quarters per row, write out, flag tight margins ----
    if (tid < BM) {
        float b1 = INFINITY, b2 = INFINITY; int i1 = 0;
        #pragma unroll
        for (int ww = 0; ww < 4; ++ww) {
            float a1 = rv1[ww][tid], a2 = rv2[ww][tid];
            int   ai = ridx[ww][tid];
            b2 = fminf(fminf(b2, a2), fmaxf(b1, a1));
            if (a1 < b1 || (a1 == b1 && ai < i1)) { b1 = a1; i1 = ai; }
        }
        out[rowBase + tid] = i1;
        if (b2 - b1 < TAU) {
            int p = atomicAdd(count, 1);
            list[p] = rowBase + tid;
        }
    }
}

// ---------------------------------------------------------------------------
// Rescue: exact fp32 recompute for flagged rows (expected ~100-300 rows).
// ---------------------------------------------------------------------------
__global__ void rescue_kernel(const float* __restrict__ x, const float* __restrict__ c,
                              const char* __restrict__ ws, int* __restrict__ out) {
    __shared__ float xrow[DIM];
    __shared__ float rv[256];
    __shared__ int   ri[256];
    const float* csq = (const float*)(ws + WS_CSQ);
    const int* list  = (const int*)(ws + WS_LIST);
    const int n = *(const int*)ws;
    const int tid = threadIdx.x;

    for (int it = blockIdx.x; it < n; it += gridDim.x) {
        int row = list[it];
        for (int d = tid; d < DIM; d += 256) xrow[d] = x[(size_t)row * DIM + d];
        __syncthreads();

        float bv = INFINITY; int bi = 0;
        for (int k = tid; k < K_C; k += 256) {
            const float* crow = c + (size_t)k * DIM;
            float dot = 0.f;
            #pragma unroll 4
            for (int d = 0; d < DIM; d += 4) {
                float4 cv = *reinterpret_cast<const float4*>(&crow[d]);
                dot = fmaf(xrow[d + 0], cv.x, dot);
                dot = fmaf(xrow[d + 1], cv.y, dot);
                dot = fmaf(xrow[d + 2], cv.z, dot);
                dot = fmaf(xrow[d + 3], cv.w, dot);
            }
            float dist = fmaf(-2.f, dot, csq[k]);
            if (dist < bv || (dist == bv && k < bi)) { bv = dist; bi = k; }
        }
        rv[tid] = bv; ri[tid] = bi;
        __syncthreads();
        for (int s = 128; s; s >>= 1) {
            if (tid < s) {
                if (rv[tid + s] < rv[tid] ||
                    (rv[tid + s] == rv[tid] && ri[tid + s] < ri[tid])) {
                    rv[tid] = rv[tid + s]; ri[tid] = ri[tid + s];
                }
            }
            __syncthreads();
        }
        if (tid == 0) out[row] = ri[0];
        __syncthreads();
    }
}

extern "C" void kernel_launch(void* const* d_in, const int* in_sizes, int n_in,
                              void* d_out, int out_size, void* d_ws, size_t ws_size,
                              hipStream_t stream) {
    const float* x = (const float*)d_in[0];
    const float* c = (const float*)d_in[1];
    char* ws = (char*)d_ws;
    int* out = (int*)d_out;

    convert_kernel<<<dim3(192), dim3(256), 0, stream>>>(
        c, (ushort*)(ws + WS_CHI), (ushort*)(ws + WS_CLO), (int*)ws);
    csq_kernel<<<dim3(128), dim3(256), 0, stream>>>(c, (float*)(ws + WS_CSQ));
    kmeans_mfma<<<dim3(NROWS / BM), dim3(THREADS), 0, stream>>>(x, ws, out);
    rescue_kernel<<<dim3(512), dim3(256), 0, stream>>>(x, c, ws, out);
}